// Round 1
// baseline (460.638 us; speedup 1.0000x reference)
//
#include <hip/hip_runtime.h>

#define TT 256
#define BB 32
#define KK 128
#define FSMALL 1.1754943508222875e-38f   // np.finfo(float32).tiny

// One block per batch chain. 1024 threads:
//   kq = tid & 31  -> owns columns 4*kq .. 4*kq+3  (k' dim)
//   kg = tid >> 5  -> owns rows    4*kg .. 4*kg+3  (k  dim, reduction)
// Per step: prefetched 4x float4 of transitions tile, 16 FMAs vs w[row],
// partial sums in LDS, wave 0 finalizes (log, +m, +e), computes new max,
// weights w = exp(f - m), and the prefix-logprob increment.
__global__ __launch_bounds__(1024, 1)
void hmm_fwd_kernel(const float* __restrict__ trans,   // [T,B,K,K]
                    const float* __restrict__ emis,    // [T,B,K]
                    const float* __restrict__ start,   // [1,K]
                    float* __restrict__ out0,          // [T,B]
                    float* __restrict__ fm)            // [T,B,K]
{
    const int b   = blockIdx.x;
    const int tid = threadIdx.x;
    const int kq  = tid & 31;
    const int kg  = tid >> 5;

    __shared__ float w_lds[KK];            // exp(f_prev - m), indexed by row k
    __shared__ float partial[32][KK];      // [kg][col], 16 KiB

    const size_t tile    = (size_t)KK * KK;        // 16384 floats per (t,b)
    const size_t tstride = (size_t)BB * tile;      // stride between t steps
    const float* tbase   = trans + (size_t)b * tile;
    const int    off0    = (4 * kg) * KK + 4 * kq; // row 4kg, col 4kq

    float4 A0, A1, A2, A3, B0, B1, B2, B3;

#define PRELOAD(R0, R1, R2, R3, step) do {                                   \
        const float* _p = tbase + (size_t)(step) * tstride + off0;           \
        R0 = *(const float4*)(_p);                                           \
        R1 = *(const float4*)(_p + KK);                                      \
        R2 = *(const float4*)(_p + 2 * KK);                                  \
        R3 = *(const float4*)(_p + 3 * KK);                                  \
    } while (0)

    // wave-0 persistent state (only meaningful for tid < 64)
    float m_run = 0.f, ll_prev = 0.f, sw_run = 0.f;

    // ---------------- step 0: f0 = log(start + eps) + emis[0] ----------------
    if (tid < 64) {
        const size_t erow = ((size_t)0 * BB + b) * KK;
        const float e0 = emis[erow + tid];
        const float e1 = emis[erow + tid + 64];
        float f0 = __logf(start[tid] + FSMALL) + e0;
        float f1 = __logf(start[tid + 64] + FSMALL) + e1;
        fm[erow + tid]      = f0;
        fm[erow + tid + 64] = f1;
        float mx = fmaxf(f0, f1);
        #pragma unroll
        for (int o = 32; o >= 1; o >>= 1) mx = fmaxf(mx, __shfl_xor(mx, o));
        float u0 = __expf(f0 - mx), u1 = __expf(f1 - mx);
        w_lds[tid]      = u0;
        w_lds[tid + 64] = u1;
        float sw = u0 + u1;
        #pragma unroll
        for (int o = 32; o >= 1; o >>= 1) sw += __shfl_xor(sw, o);
        float ll = mx + __logf(sw);
        if (tid == 0) out0[b] = ll;        // prefix[0] - 0
        ll_prev = ll; m_run = mx; sw_run = sw;
    }
    __syncthreads();

#define STEP(i, R0, R1, R2, R3) do {                                         \
        float e0 = 0.f, e1 = 0.f;                                            \
        if (tid < 64) {                                                      \
            const size_t erow = ((size_t)(i) * BB + b) * KK;                 \
            e0 = emis[erow + tid];                                           \
            e1 = emis[erow + tid + 64];                                      \
        }                                                                    \
        const float w0 = w_lds[4 * kg + 0];                                  \
        const float w1 = w_lds[4 * kg + 1];                                  \
        const float w2 = w_lds[4 * kg + 2];                                  \
        const float w3 = w_lds[4 * kg + 3];                                  \
        float4 acc;                                                          \
        acc.x = R0.x * w0 + R1.x * w1 + R2.x * w2 + R3.x * w3;               \
        acc.y = R0.y * w0 + R1.y * w1 + R2.y * w2 + R3.y * w3;               \
        acc.z = R0.z * w0 + R1.z * w1 + R2.z * w2 + R3.z * w3;               \
        acc.w = R0.w * w0 + R1.w * w1 + R2.w * w2 + R3.w * w3;               \
        *(float4*)&partial[kg][4 * kq] = acc;                                \
        __syncthreads();                                                     \
        if (tid < 64) {                                                      \
            float s0 = 0.f, s1 = 0.f;                                        \
            _Pragma("unroll")                                                \
            for (int g = 0; g < 32; ++g) {                                   \
                s0 += partial[g][tid];                                       \
                s1 += partial[g][tid + 64];                                  \
            }                                                                \
            s0 += FSMALL * sw_run;  /* the +eps term: eps * sum(w) */        \
            s1 += FSMALL * sw_run;                                           \
            float f0 = __logf(s0) + m_run + e0;                              \
            float f1 = __logf(s1) + m_run + e1;                              \
            const size_t frow = ((size_t)(i) * BB + b) * KK;                 \
            fm[frow + tid]      = f0;                                        \
            fm[frow + tid + 64] = f1;                                        \
            float mx = fmaxf(f0, f1);                                        \
            _Pragma("unroll")                                                \
            for (int o = 32; o >= 1; o >>= 1)                                \
                mx = fmaxf(mx, __shfl_xor(mx, o));                           \
            float u0 = __expf(f0 - mx), u1 = __expf(f1 - mx);                \
            w_lds[tid]      = u0;                                            \
            w_lds[tid + 64] = u1;                                            \
            float sw = u0 + u1;                                              \
            _Pragma("unroll")                                                \
            for (int o = 32; o >= 1; o >>= 1) sw += __shfl_xor(sw, o);       \
            float ll = mx + __logf(sw);                                      \
            if (tid == 0) out0[(size_t)(i) * BB + b] = ll - ll_prev;         \
            ll_prev = ll; m_run = mx; sw_run = sw;                           \
        }                                                                    \
        __syncthreads();                                                     \
    } while (0)

    // --------------- main recursion: step i uses transitions[i-1] -------------
    PRELOAD(A0, A1, A2, A3, 0);            // trans[0] -> consumed by STEP(1)
    int i = 1;
    for (; i + 1 < TT; i += 2) {
        PRELOAD(B0, B1, B2, B3, i);        // trans[i]   -> STEP(i+1)
        STEP(i, A0, A1, A2, A3);
        PRELOAD(A0, A1, A2, A3, i + 1);    // trans[i+1] -> STEP(i+2)
        STEP(i + 1, B0, B1, B2, B3);
    }
    STEP(TT - 1, A0, A1, A2, A3);          // final odd step

#undef PRELOAD
#undef STEP
}

extern "C" void kernel_launch(void* const* d_in, const int* in_sizes, int n_in,
                              void* d_out, int out_size, void* d_ws, size_t ws_size,
                              hipStream_t stream) {
    // d_in order: sequences (unused), transitions, emissions, start_transitions
    const float* trans = (const float*)d_in[1];
    const float* emis  = (const float*)d_in[2];
    const float* start = (const float*)d_in[3];
    float* out0 = (float*)d_out;                         // [T,B]
    float* fm   = (float*)d_out + (size_t)TT * BB;       // [T,B,K]
    hipLaunchKernelGGL(hmm_fwd_kernel, dim3(BB), dim3(1024), 0, stream,
                       trans, emis, start, out0, fm);
}

// Round 2
// 363.426 us; speedup vs baseline: 1.2675x; 1.2675x over previous
//
#include <hip/hip_runtime.h>

#define TT 256
#define BB 32
#define KK 128
#define FSMALL 1.1754943508222875e-38f   // np.finfo(float32).tiny

// One block per batch. 1024 threads = 8 row-groups x 128 columns.
// Thread (g, j): rows 16g..16g+15 of the transition tile, column j.
// Lagged-max online rescaling: weights u_i = exp(f_i - R_i) with
// R_i = max_k f_{i-1}[k] (one-step-stale reference, exact algebra):
//   s_i[j]  = sum_k t[k][j] * u_{i-1}[k]            (the GEMV)
//   u_i[j]  = (s_i[j] + eps*sum(u_{i-1})) * exp(e_i[j] - log maxu_{i-1})
//   f_i[j]  = log(s_i[j] + eps*sum) + R_{i-1} + e_i[j]
//   ll_i    = R_i + log(sum_j u_i[j])
// max/sum reductions of u_i are consumed one step later -> off critical path.
__global__ __launch_bounds__(1024, 1)
void hmm_fwd_kernel(const float* __restrict__ trans,   // [T,B,K,K]
                    const float* __restrict__ emis,    // [T,B,K]
                    const float* __restrict__ start,   // [1,K]
                    float* __restrict__ out0,          // [T,B]
                    float* __restrict__ fm)            // [T,B,K]
{
    const int b   = blockIdx.x;
    const int tid = threadIdx.x;
    const int g   = tid >> 7;      // row group 0..7
    const int jc  = tid & 127;     // column 0..127
    const bool fin = (tid < KK);   // waves 0,1 do the finalize

    __shared__ __align__(16) float w_lds[KK];
    __shared__ float partial[8 * KK];
    __shared__ float slots[4];     // {maxu_w0, sumu_w0, maxu_w1, sumu_w1}

    const size_t tile    = (size_t)KK * KK;
    const size_t tstride = (size_t)BB * tile;
    const float* tbase   = trans + (size_t)b * tile + (size_t)(g * 16) * KK + jc;

    float A[16], Bb[16], C[16];
    float R = 0.f, Rold = 0.f, ll_prev = 0.f;
    float e_cur = 0.f, e_nxt = 0.f, pe = 0.f, ceps = 0.f;

#define PRELOAD(BUF, step) do {                                              \
        const float* _p = tbase + (size_t)(step) * tstride;                  \
        _Pragma("unroll")                                                    \
        for (int _r = 0; _r < 16; ++_r) BUF[_r] = _p[_r * KK];               \
    } while (0)

    // -------- init: step 0: f0 = log(start+eps) + e0 --------
    float f0v = 0.f;
    if (fin) {
        float e0 = emis[(size_t)b * KK + jc];
        e_cur    = emis[((size_t)1 * BB + b) * KK + jc];   // e_1 for step 1
        f0v = __logf(start[jc] + FSMALL) + e0;
        fm[(size_t)b * KK + jc] = f0v;
        float mf = f0v;
        #pragma unroll
        for (int o = 32; o >= 1; o >>= 1) mf = fmaxf(mf, __shfl_xor(mf, o));
        if ((tid & 63) == 0) slots[(tid >> 6) * 2] = mf;
    }
    __syncthreads();
    float mu0 = 0.f, su0 = 0.f;
    if (fin) {
        float m0 = fmaxf(slots[0], slots[2]);   // true max of f0
        R = m0;                                 // reference for u_1
        float u = __expf(f0v - m0);
        w_lds[jc] = u;
        mu0 = u; su0 = u;
        #pragma unroll
        for (int o = 32; o >= 1; o >>= 1) {
            mu0 = fmaxf(mu0, __shfl_xor(mu0, o));
            su0 += __shfl_xor(su0, o);
        }
    }
    __syncthreads();
    if (fin && (tid & 63) == 0) {
        slots[(tid >> 6) * 2]     = mu0;   // = 1.0
        slots[(tid >> 6) * 2 + 1] = su0;
    }
    PRELOAD(A, 0);     // trans[0] -> STEP(1)
    PRELOAD(Bb, 1);    // trans[1] -> STEP(2)
    __syncthreads();

#define STEP(i, CUR, NXT) do {                                               \
        { int _ls = ((i) + 1 < TT) ? (i) + 1 : TT - 1;                       \
          PRELOAD(NXT, _ls); }                                               \
        if (fin) {                                                           \
            float _s0 = slots[0], _s1 = slots[1];                            \
            float _s2 = slots[2], _s3 = slots[3];                            \
            float _maxu = fmaxf(_s0, _s2);                                   \
            float _sumu = _s1 + _s3;                                         \
            float _lmax = __logf(_maxu);                                     \
            Rold = R; R += _lmax;                                            \
            pe   = __expf(e_cur - _lmax);                                    \
            ceps = FSMALL * _sumu;                                           \
            if (tid == 0) {                                                  \
                float _ll = Rold + __logf(_sumu);                            \
                out0[(size_t)((i) - 1) * BB + b] = _ll - ll_prev;            \
                ll_prev = _ll;                                               \
            }                                                                \
            e_nxt = emis[(size_t)(((i) + 1 < TT ? (i) + 1 : (i)) * BB + b)   \
                         * KK + jc];                                         \
        }                                                                    \
        {                                                                    \
            const float4* _wp = (const float4*)&w_lds[g * 16];               \
            float4 _w0 = _wp[0], _w1 = _wp[1], _w2 = _wp[2], _w3 = _wp[3];   \
            float _a0 = _w0.x*CUR[0]  + _w0.y*CUR[1]                         \
                      + _w0.z*CUR[2]  + _w0.w*CUR[3];                        \
            float _a1 = _w1.x*CUR[4]  + _w1.y*CUR[5]                         \
                      + _w1.z*CUR[6]  + _w1.w*CUR[7];                        \
            float _a2 = _w2.x*CUR[8]  + _w2.y*CUR[9]                         \
                      + _w2.z*CUR[10] + _w2.w*CUR[11];                       \
            float _a3 = _w3.x*CUR[12] + _w3.y*CUR[13]                        \
                      + _w3.z*CUR[14] + _w3.w*CUR[15];                       \
            partial[g * KK + jc] = (_a0 + _a1) + (_a2 + _a3);                \
        }                                                                    \
        __syncthreads();                                                     \
        if (fin) {                                                           \
            float _p0 = partial[0*KK+jc], _p1 = partial[1*KK+jc];            \
            float _p2 = partial[2*KK+jc], _p3 = partial[3*KK+jc];            \
            float _p4 = partial[4*KK+jc], _p5 = partial[5*KK+jc];            \
            float _p6 = partial[6*KK+jc], _p7 = partial[7*KK+jc];            \
            float _s  = ((_p0+_p1)+(_p2+_p3)) + ((_p4+_p5)+(_p6+_p7));       \
            float _sc = _s + ceps;                                           \
            float _u  = _sc * pe;            /* critical path ends here */   \
            w_lds[jc] = _u;                                                  \
            float _f = __logf(_sc) + Rold + e_cur;      /* off-path tail */  \
            fm[((size_t)(i) * BB + b) * KK + jc] = _f;                       \
            float _mu = _u, _su = _u;                                        \
            _Pragma("unroll")                                                \
            for (int _o = 32; _o >= 1; _o >>= 1) {                           \
                _mu = fmaxf(_mu, __shfl_xor(_mu, _o));                       \
                _su += __shfl_xor(_su, _o);                                  \
            }                                                                \
            if ((tid & 63) == 0) {                                           \
                slots[(tid >> 6) * 2]     = _mu;                             \
                slots[(tid >> 6) * 2 + 1] = _su;                             \
            }                                                                \
            e_cur = e_nxt;                                                   \
        }                                                                    \
        __syncthreads();                                                     \
    } while (0)

    // -------- main recursion: steps 1..255, 3-deep prefetch rotation ------
    #pragma unroll 1
    for (int m = 0; m < 85; ++m) {
        const int i0 = 3 * m + 1;
        STEP(i0,     A,  C);
        STEP(i0 + 1, Bb, A);
        STEP(i0 + 2, C,  Bb);
    }

    // -------- epilogue: last prefix increment (uses TAIL_255 slots) -------
    if (tid == 0) {
        float sumu = slots[1] + slots[3];
        float ll = R + __logf(sumu);
        out0[(size_t)(TT - 1) * BB + b] = ll - ll_prev;
    }

#undef PRELOAD
#undef STEP
}

extern "C" void kernel_launch(void* const* d_in, const int* in_sizes, int n_in,
                              void* d_out, int out_size, void* d_ws, size_t ws_size,
                              hipStream_t stream) {
    // d_in order: sequences (unused), transitions, emissions, start_transitions
    const float* trans = (const float*)d_in[1];
    const float* emis  = (const float*)d_in[2];
    const float* start = (const float*)d_in[3];
    float* out0 = (float*)d_out;                         // [T,B]
    float* fm   = (float*)d_out + (size_t)TT * BB;       // [T,B,K]
    hipLaunchKernelGGL(hmm_fwd_kernel, dim3(BB), dim3(1024), 0, stream,
                       trans, emis, start, out0, fm);
}